// Round 1
// baseline (37.045 us; speedup 1.0000x reference)
//
#include <hip/hip_runtime.h>

#define SIZE_IN   8192
#define SIZE_OUT  2048
#define JT        2                  // j tiles per i-chunk
#define JTILE     (SIZE_OUT / JT)    // 1024 floats = 256 float4
#define BLOCK     256

// Kernel 1: each block handles one (i-chunk, j-tile). Each thread owns one
// float4 of j. Partial sums go to ws[chunk][j] (overwritten every call).
__global__ __launch_bounds__(BLOCK) void ill_partial(
    const float* __restrict__ x,
    const int*   __restrict__ idx,
    const float* __restrict__ w,
    float*       __restrict__ ws,
    int ch)   // i's per chunk
{
    const int jt  = blockIdx.x & (JT - 1);
    const int ic  = blockIdx.x / JT;
    const int tid = threadIdx.x;
    const int j   = jt * JTILE + tid * 4;
    const int i0  = ic * ch;

    float4 acc = make_float4(0.f, 0.f, 0.f, 0.f);

    #pragma unroll 8
    for (int k = 0; k < ch; ++k) {
        const int    i  = i0 + k;
        const float  xv = x[i];
        const int    q  = idx[i];
        const float4 wv = *reinterpret_cast<const float4*>(
            w + ((size_t)q * SIZE_IN + (size_t)i) * SIZE_OUT + j);
        acc.x += xv * wv.x;
        acc.y += xv * wv.y;
        acc.z += xv * wv.z;
        acc.w += xv * wv.w;
    }

    *reinterpret_cast<float4*>(ws + (size_t)ic * SIZE_OUT + j) = acc;
}

// Kernel 2: out[j] = bias[j] + sum over chunks of ws[chunk][j]
__global__ __launch_bounds__(BLOCK) void ill_reduce(
    const float* __restrict__ ws,
    const float* __restrict__ bias,
    float*       __restrict__ out,
    int nsplit)
{
    const int j = blockIdx.x * BLOCK + threadIdx.x;
    float s = bias[j];
    #pragma unroll 8
    for (int k = 0; k < nsplit; ++k)
        s += ws[(size_t)k * SIZE_OUT + j];
    out[j] = s;
}

extern "C" void kernel_launch(void* const* d_in, const int* in_sizes, int n_in,
                              void* d_out, int out_size, void* d_ws, size_t ws_size,
                              hipStream_t stream) {
    const float* x    = (const float*)d_in[0];
    const int*   idx  = (const int*)d_in[1];
    const float* w    = (const float*)d_in[2];
    const float* bias = (const float*)d_in[3];
    float* out = (float*)d_out;
    float* ws  = (float*)d_ws;

    // Choose the i-chunk size so partials fit in the workspace.
    int ch = 32;                                   // preferred: 256 chunks -> 2 MiB ws
    while (ch < SIZE_IN &&
           (size_t)(SIZE_IN / ch) * SIZE_OUT * sizeof(float) > ws_size) {
        ch <<= 1;
    }
    const int nsplit = SIZE_IN / ch;

    ill_partial<<<dim3(nsplit * JT), dim3(BLOCK), 0, stream>>>(x, idx, w, ws, ch);
    ill_reduce<<<dim3(SIZE_OUT / BLOCK), dim3(BLOCK), 0, stream>>>(ws, bias, out, nsplit);
}

// Round 2
// 21.300 us; speedup vs baseline: 1.7392x; 1.7392x over previous
//
#include <hip/hip_runtime.h>

#define SIZE_IN   8192
#define SIZE_OUT  2048
#define JT        2                  // j tiles per i-chunk
#define JTILE     (SIZE_OUT / JT)    // 1024 floats = 256 float4
#define BLOCK     256

// Kernel 1: each block handles one (i-chunk, j-tile). Each thread owns one
// float4 of j. Partial sums go to ws[chunk][j] (overwritten every call).
__global__ __launch_bounds__(BLOCK) void ill_partial(
    const float* __restrict__ x,
    const int*   __restrict__ idx,
    const float* __restrict__ w,
    float*       __restrict__ ws,
    int ch)   // i's per chunk
{
    const int jt  = blockIdx.x & (JT - 1);
    const int ic  = blockIdx.x / JT;
    const int tid = threadIdx.x;
    const int j   = jt * JTILE + tid * 4;
    const int i0  = ic * ch;

    float4 acc = make_float4(0.f, 0.f, 0.f, 0.f);

    #pragma unroll 8
    for (int k = 0; k < ch; ++k) {
        const int    i  = i0 + k;
        const float  xv = x[i];
        const size_t q  = (size_t)idx[i];
        const float4 wv = *reinterpret_cast<const float4*>(
            w + ((q << 13) + (size_t)i) * (size_t)SIZE_OUT + j);
        acc.x += xv * wv.x;
        acc.y += xv * wv.y;
        acc.z += xv * wv.z;
        acc.w += xv * wv.w;
    }

    *reinterpret_cast<float4*>(ws + (size_t)ic * SIZE_OUT + j) = acc;
}

// Kernel 2: one WAVE per float4 output column. Lane l sums splits
// {l, l+64, ...}, then a 64-lane shuffle tree finishes the column.
// Grid = 512 columns / 4 waves-per-block = 128 blocks.
__global__ __launch_bounds__(BLOCK) void ill_reduce(
    const float* __restrict__ ws,
    const float* __restrict__ bias,
    float*       __restrict__ out,
    int nsplit)
{
    const int lane = threadIdx.x & 63;
    const int j4   = blockIdx.x * (BLOCK / 64) + (threadIdx.x >> 6);
    const float4* ws4 = reinterpret_cast<const float4*>(ws);

    float4 acc = make_float4(0.f, 0.f, 0.f, 0.f);
    for (int s = lane; s < nsplit; s += 64) {
        const float4 v = ws4[(size_t)s * (SIZE_OUT / 4) + j4];
        acc.x += v.x; acc.y += v.y; acc.z += v.z; acc.w += v.w;
    }

    #pragma unroll
    for (int off = 32; off > 0; off >>= 1) {
        acc.x += __shfl_down(acc.x, off, 64);
        acc.y += __shfl_down(acc.y, off, 64);
        acc.z += __shfl_down(acc.z, off, 64);
        acc.w += __shfl_down(acc.w, off, 64);
    }

    if (lane == 0) {
        const float4 b = reinterpret_cast<const float4*>(bias)[j4];
        reinterpret_cast<float4*>(out)[j4] =
            make_float4(acc.x + b.x, acc.y + b.y, acc.z + b.z, acc.w + b.w);
    }
}

extern "C" void kernel_launch(void* const* d_in, const int* in_sizes, int n_in,
                              void* d_out, int out_size, void* d_ws, size_t ws_size,
                              hipStream_t stream) {
    const float* x    = (const float*)d_in[0];
    const int*   idx  = (const int*)d_in[1];
    const float* w    = (const float*)d_in[2];
    const float* bias = (const float*)d_in[3];
    float* out = (float*)d_out;
    float* ws  = (float*)d_ws;

    // i-chunk size: prefer 16 (nsplit=512, grid=1024 blocks); grow chunks if
    // the workspace can't hold the partials.
    int ch = 16;
    while (ch < SIZE_IN &&
           (size_t)(SIZE_IN / ch) * SIZE_OUT * sizeof(float) > ws_size) {
        ch <<= 1;
    }
    const int nsplit = SIZE_IN / ch;

    ill_partial<<<dim3(nsplit * JT), dim3(BLOCK), 0, stream>>>(x, idx, w, ws, ch);
    ill_reduce<<<dim3((SIZE_OUT / 4) / (BLOCK / 64)), dim3(BLOCK), 0, stream>>>(
        ws, bias, out, nsplit);
}